// Round 3
// baseline (345.859 us; speedup 1.0000x reference)
//
#include <hip/hip_runtime.h>

#define KTAPS 9
#define DIL 6
#define BN_EPS 1e-5f
#define BB 8
#define CIN 256
#define COUT 256
#define NPTS 8192
#define BN 128
#define XW 192       // x window cols (BN + 2*XOFF)
#define XOFF 32      // window col 0 = n0 - XOFF
#define BSTRIDE 40   // B row stride in shorts (R0-verified layout)

typedef __attribute__((ext_vector_type(8))) short short8;
typedef __attribute__((ext_vector_type(4))) float f32x4;

__device__ __forceinline__ unsigned short f2bf(float f) {
  union { float f; unsigned u; } v; v.f = f;
  unsigned r = v.u + 0x7fffu + ((v.u >> 16) & 1u);   // RNE
  return (unsigned short)(r >> 16);
}

// ---------------------------------------------------------------- pre: pack W + zero sums
// Wa[chunk][mi][kk]; chunk = ktap*8 + c8; element = W[mi][c8*32+kk][ktap]
__global__ __launch_bounds__(256)
void pre_kernel(const float* __restrict__ W, short* __restrict__ Wa,
                float* __restrict__ sums) {
  int bid = blockIdx.x;
  if (bid < 2304) {
    int idx = bid * 256 + threadIdx.x;
    int kk = idx & 31;
    int mi = (idx >> 5) & 255;
    int chunk = idx >> 13;
    int ktap = chunk >> 3;
    int c = ((chunk & 7) << 5) + kk;
    Wa[idx] = (short)f2bf(W[(size_t)mi * (CIN * KTAPS) + c * KTAPS + ktap]);
  } else {
    if (threadIdx.x < 512) sums[threadIdx.x] = 0.f;
  }
}

// ---------------------------------------------------------------- MFMA conv
// R0 pipelined structure (build tap k+1 || MFMA tap k) with:
//  - A fragments in registers, triple-buffered, loaded from L2-resident Wa
//  - x window double-buffered f32 in LDS; next-c8 loads issued at tap 0,
//    written at tap 7, B[0] of next c8 built at tap 8 (no c8 turnaround)
//  - per-tap barriers are raw lgkmcnt(0)+s_barrier (no vmcnt drain ->
//    stage loads stay in flight across barriers)
__global__ __launch_bounds__(256, 2)
void conv_mfma(const float* __restrict__ x, const float* __restrict__ coords,
               const float* __restrict__ rot, const float* __restrict__ dist,
               const short* __restrict__ Wa, const float* __restrict__ bias,
               float* __restrict__ out,
               float* __restrict__ sums1, float* __restrict__ sums2) {
  __shared__ float x_win[2][32][XW];          // 48 KB  x window dbuf (f32, exact numerics)
  __shared__ short B_lds[2][BN][BSTRIDE];     // 20 KB  per-tap B dbuf

  const int tid = threadIdx.x;
  const int b = blockIdx.y;
  const int n0 = blockIdx.x * BN;
  const int wave = tid >> 6;
  const int lane = tid & 63;
  const int col = lane & 15;
  const int quad = lane >> 4;
  const int tl = lane;              // n-pair index for B-build (rows 2tl, 2tl+1)
  const int tkk = wave * 8;         // kk granule base for B-build
  const int xchl = tid >> 3;        // x-stage channel 0..31
  const int xc0 = (tid & 7) * 4;    // x-stage col base

  // ---- per-thread tap weights g[k][i] for n = n0 + 2tl + i  (R0-verified)
  float greg[KTAPS][2];
  {
    const float* cb = coords + (size_t)b * 3 * NPTS;
    const float* rb = rot + (size_t)b * 3 * NPTS;
    const float* db = dist + (size_t)b * NPTS;
#pragma unroll
    for (int i = 0; i < 2; ++i) {
      int n = n0 + 2 * tl + i;
      float c0x = cb[n], c0y = cb[NPTS + n], c0z = cb[2 * NPTS + n];
      float r0x = rb[n], r0y = rb[NPTS + n], r0z = rb[2 * NPTS + n];
      float d0 = db[n];
      float r0n = r0x * r0x + r0y * r0y + r0z * r0z;
#pragma unroll
      for (int k = 0; k < KTAPS; ++k) {
        int j = n + (k - KTAPS / 2) * DIL;
        float gv = 0.f;
        if (j >= 0 && j < NPTS) {
          float dcx = c0x - cb[j], dcy = c0y - cb[NPTS + j], dcz = c0z - cb[2 * NPTS + j];
          float dc = dcx * dcx + dcy * dcy + dcz * dcz;
          float dd = d0 - db[j];
          dd *= dd;
          float gauss = expf(-(dc + dd) * 0.5f);
          float rjx = rb[j], rjy = rb[NPTS + j], rjz = rb[2 * NPTS + j];
          float num = r0x * rjx + r0y * rjy + r0z * rjz;
          float den = sqrtf(r0n * (rjx * rjx + rjy * rjy + rjz * rjz)) + 1e-8f;
          gv = gauss * fabsf(num / den);
        }
        greg[k][i] = gv;
      }
    }
  }

  const float* xb = x + (size_t)b * CIN * NPTS;
  const int arow0 = (wave * 64 + col) * 32 + quad * 8;  // short offset in a Wa chunk

  float4 xr[6];                     // global->reg stage for next c8
  short8 afA[4], afB[4], afC[4];    // A triple buffer

#define LOADAF(AF, CHUNK)                                               \
  {                                                                     \
    const short* p_ = Wa + (size_t)(CHUNK) * 8192 + arow0;              \
    _Pragma("unroll")                                                   \
    for (int m = 0; m < 4; ++m) AF[m] = *(const short8*)(p_ + m * 512); \
  }

#define STAGE_LOAD(C8)                                                  \
  {                                                                     \
    const float* xrow_ = xb + (size_t)((C8) * 32 + xchl) * NPTS;        \
    _Pragma("unroll")                                                   \
    for (int q = 0; q < 6; ++q) {                                       \
      int cw_ = xc0 + q * 32;                                           \
      int jg_ = n0 - XOFF + cw_;                                        \
      float4 v_;                                                        \
      if (jg_ >= 0 && jg_ + 3 < NPTS) {                                 \
        v_ = *(const float4*)&xrow_[jg_];                               \
      } else {                                                          \
        float* e_ = (float*)&v_;                                        \
        _Pragma("unroll")                                               \
        for (int u = 0; u < 4; ++u) {                                   \
          int jj_ = jg_ + u;                                            \
          e_[u] = (jj_ >= 0 && jj_ < NPTS) ? xrow_[jj_] : 0.f;          \
        }                                                               \
      }                                                                 \
      xr[q] = v_;                                                       \
    }                                                                   \
  }

#define STAGE_WRITE(XB)                                                 \
  {                                                                     \
    _Pragma("unroll")                                                   \
    for (int q = 0; q < 6; ++q)                                         \
      *(float4*)&x_win[XB][xchl][xc0 + q * 32] = xr[q];                 \
  }

#define BUILD(K, P, XC)                                                 \
  {                                                                     \
    const int base_ = 2 * tl + ((K)-KTAPS / 2) * DIL + XOFF;            \
    short8 p0_, p1_;                                                    \
    _Pragma("unroll")                                                   \
    for (int cc = 0; cc < 8; ++cc) {                                    \
      float2 v_ = *(const float2*)&x_win[XC][tkk + cc][base_];          \
      p0_[cc] = (short)f2bf(v_.x * greg[K][0]);                         \
      p1_[cc] = (short)f2bf(v_.y * greg[K][1]);                         \
    }                                                                   \
    *(short8*)&B_lds[P][2 * tl][tkk] = p0_;                             \
    *(short8*)&B_lds[P][2 * tl + 1][tkk] = p1_;                         \
  }

#define MFMA_TAP(P, AF)                                                 \
  {                                                                     \
    _Pragma("unroll")                                                   \
    for (int j = 0; j < 8; ++j) {                                       \
      short8 bfv_ = *(const short8*)&B_lds[P][j * 16 + col][quad * 8];  \
      _Pragma("unroll")                                                 \
      for (int m = 0; m < 4; ++m)                                       \
        acc[m][j] = __builtin_amdgcn_mfma_f32_16x16x32_bf16(AF[m], bfv_, acc[m][j], 0, 0, 0); \
    }                                                                   \
  }

// pure-LDS barrier: no vmcnt drain (stage loads stay in flight)
#define BAR()                                                           \
  {                                                                     \
    asm volatile("s_waitcnt lgkmcnt(0)" ::: "memory");                  \
    __builtin_amdgcn_s_barrier();                                       \
    __builtin_amdgcn_sched_barrier(0);                                  \
  }

#define C8BODY(C8, XC, DN)                                              \
  {                                                                     \
    const int cp_ = (C8)&1;                                             \
    /* tap 0 */                                                         \
    LOADAF(afC, 16 + (C8));                                             \
    if (DN) STAGE_LOAD((C8) + 1);                                       \
    BUILD(1, cp_ ^ 1, XC);                                              \
    MFMA_TAP(cp_, afA);                                                 \
    BAR();                                                              \
    /* tap 1 */                                                         \
    LOADAF(afA, 24 + (C8));                                             \
    BUILD(2, cp_, XC);                                                  \
    MFMA_TAP(cp_ ^ 1, afB);                                             \
    BAR();                                                              \
    /* tap 2 */                                                         \
    LOADAF(afB, 32 + (C8));                                             \
    BUILD(3, cp_ ^ 1, XC);                                              \
    MFMA_TAP(cp_, afC);                                                 \
    BAR();                                                              \
    /* tap 3 */                                                         \
    LOADAF(afC, 40 + (C8));                                             \
    BUILD(4, cp_, XC);                                                  \
    MFMA_TAP(cp_ ^ 1, afA);                                             \
    BAR();                                                              \
    /* tap 4 */                                                         \
    LOADAF(afA, 48 + (C8));                                             \
    BUILD(5, cp_ ^ 1, XC);                                              \
    MFMA_TAP(cp_, afB);                                                 \
    BAR();                                                              \
    /* tap 5 */                                                         \
    LOADAF(afB, 56 + (C8));                                             \
    BUILD(6, cp_, XC);                                                  \
    MFMA_TAP(cp_ ^ 1, afC);                                             \
    BAR();                                                              \
    /* tap 6 */                                                         \
    LOADAF(afC, 64 + (C8));                                             \
    BUILD(7, cp_ ^ 1, XC);                                              \
    MFMA_TAP(cp_, afA);                                                 \
    BAR();                                                              \
    /* tap 7 */                                                         \
    if (DN) LOADAF(afA, (C8) + 1);                                      \
    BUILD(8, cp_, XC);                                                  \
    MFMA_TAP(cp_ ^ 1, afB);                                             \
    if (DN) STAGE_WRITE((XC) ^ 1);                                      \
    BAR();                                                              \
    /* tap 8 */                                                         \
    if (DN) {                                                           \
      LOADAF(afB, 8 + (C8) + 1);                                        \
      BUILD(0, cp_ ^ 1, (XC) ^ 1);                                      \
    }                                                                   \
    MFMA_TAP(cp_, afC);                                                 \
    BAR();                                                              \
  }

  f32x4 acc[4][8];
#pragma unroll
  for (int m = 0; m < 4; ++m)
#pragma unroll
    for (int j = 0; j < 8; ++j) acc[m][j] = (f32x4)0.f;

  // ---- prologue: stage x_win[0], preload A chunks 0 and 8, build B[0]
  STAGE_LOAD(0);
  STAGE_WRITE(0);
  LOADAF(afA, 0);
  LOADAF(afB, 8);
  __syncthreads();          // x_win[0] published
  BUILD(0, 0, 0);           // B[0] of c8=0 -> buf 0
  __syncthreads();          // B[0] published

#pragma unroll 1
  for (int c4 = 0; c4 < 4; ++c4) {
    const int c8a = 2 * c4;
    const int c8b = 2 * c4 + 1;
    const bool dnb = (c4 < 3);
    C8BODY(c8a, 0, true);
    C8BODY(c8b, 1, dnb);
  }

  // ---- epilogue: bias, BN partial sums, store (R0-verified)
  const int obase = wave * 64;
  float* outp = out + (size_t)b * COUT * NPTS + n0;
#pragma unroll
  for (int m = 0; m < 4; ++m) {
    const int o0 = obase + m * 16 + quad * 4;
    const float4 bv = *(const float4*)&bias[o0];
#pragma unroll
    for (int j = 0; j < 8; ++j) {
      acc[m][j][0] += bv.x; acc[m][j][1] += bv.y;
      acc[m][j][2] += bv.z; acc[m][j][3] += bv.w;
    }
#pragma unroll
    for (int r = 0; r < 4; ++r) {
      float s1 = 0.f, s2 = 0.f;
#pragma unroll
      for (int j = 0; j < 8; ++j) {
        float v = acc[m][j][r];
        s1 += v; s2 += v * v;
      }
      s1 += __shfl_xor(s1, 1); s2 += __shfl_xor(s2, 1);
      s1 += __shfl_xor(s1, 2); s2 += __shfl_xor(s2, 2);
      s1 += __shfl_xor(s1, 4); s2 += __shfl_xor(s2, 4);
      s1 += __shfl_xor(s1, 8); s2 += __shfl_xor(s2, 8);
      if (col == 0) {
        atomicAdd(&sums1[o0 + r], s1);
        atomicAdd(&sums2[o0 + r], s2);
      }
#pragma unroll
      for (int j = 0; j < 8; ++j)
        outp[(size_t)(o0 + r) * NPTS + j * 16 + col] = acc[m][j][r];
    }
  }
}

// ---------------------------------------------------------------- BN + ReLU
__global__ __launch_bounds__(256)
void bn_apply(float* __restrict__ out, const float* __restrict__ sums1,
              const float* __restrict__ sums2, const float* __restrict__ gamma,
              const float* __restrict__ beta) {
  int bo = blockIdx.x;
  int o = bo & (COUT - 1);
  const float inv = 1.f / (float)(BB * NPTS);
  float mean = sums1[o] * inv;
  float var = sums2[o] * inv - mean * mean;
  float scale = gamma[o] * rsqrtf(var + BN_EPS);
  float shift = beta[o] - mean * scale;
  float4* p = (float4*)(out + (size_t)bo * NPTS);
  for (int i = threadIdx.x; i < NPTS / 4; i += blockDim.x) {
    float4 v = p[i];
    v.x = fmaxf(fmaf(v.x, scale, shift), 0.f);
    v.y = fmaxf(fmaf(v.y, scale, shift), 0.f);
    v.z = fmaxf(fmaf(v.z, scale, shift), 0.f);
    v.w = fmaxf(fmaf(v.w, scale, shift), 0.f);
    p[i] = v;
  }
}

// ---------------------------------------------------------------- launch
extern "C" void kernel_launch(void* const* d_in, const int* in_sizes, int n_in,
                              void* d_out, int out_size, void* d_ws, size_t ws_size,
                              hipStream_t stream) {
  const float* x      = (const float*)d_in[0];
  const float* coords = (const float*)d_in[1];
  const float* rot    = (const float*)d_in[2];
  const float* dist   = (const float*)d_in[3];
  const float* W      = (const float*)d_in[4];
  const float* bias   = (const float*)d_in[5];
  const float* gamma  = (const float*)d_in[6];
  const float* beta   = (const float*)d_in[7];
  float* out = (float*)d_out;

  float* ws    = (float*)d_ws;
  float* sums1 = ws;                    // 256
  float* sums2 = ws + 256;              // 256
  short* Wa    = (short*)(ws + 512);    // 72*8192 bf16

  pre_kernel<<<2305, 256, 0, stream>>>(W, Wa, sums1);
  conv_mfma<<<dim3(NPTS / BN, BB), 256, 0, stream>>>(x, coords, rot, dist, Wa, bias, out, sums1, sums2);
  bn_apply<<<BB * COUT, 256, 0, stream>>>(out, sums1, sums2, gamma, beta);
}

// Round 4
// 271.900 us; speedup vs baseline: 1.2720x; 1.2720x over previous
//
#include <hip/hip_runtime.h>

#define KTAPS 9
#define DIL 6
#define BN_EPS 1e-5f
#define BB 8
#define CIN 256
#define COUT 256
#define NPTS 8192
#define BN 128
#define XW 192       // x window cols (BN + 2*XOFF)
#define XOFF 32      // window col 0 = n0 - XOFF
#define BSTRIDE 40   // B row stride in shorts (80 B; 16B-aligned granules)

typedef __attribute__((ext_vector_type(8))) short short8;
typedef __attribute__((ext_vector_type(4))) float f32x4;

__device__ __forceinline__ unsigned short f2bf(float f) {
  union { float f; unsigned u; } v; v.f = f;
  unsigned r = v.u + 0x7fffu + ((v.u >> 16) & 1u);   // RNE
  return (unsigned short)(r >> 16);
}

// ---------------------------------------------------------------- pre: pack W + zero sums
// Wa[chunk][mi][kk]; chunk = ktap*8 + c8; element = W[mi][c8*32+kk][ktap]
__global__ __launch_bounds__(256)
void pre_kernel(const float* __restrict__ W, short* __restrict__ Wa,
                float* __restrict__ sums) {
  int bid = blockIdx.x;
  if (bid < 2304) {
    int idx = bid * 256 + threadIdx.x;
    int kk = idx & 31;
    int mi = (idx >> 5) & 255;
    int chunk = idx >> 13;
    int ktap = chunk >> 3;
    int c = ((chunk & 7) << 5) + kk;
    Wa[idx] = (short)f2bf(W[(size_t)mi * (CIN * KTAPS) + c * KTAPS + ktap]);
  } else {
    if (threadIdx.x < 512) sums[threadIdx.x] = 0.f;
  }
}

// ---------------------------------------------------------------- MFMA conv
// Per-tap pipeline (build k+1 || MFMA k), A in registers (double-buffered from
// L2-resident Wa), x window dbuf in LDS (two-half staging to cap VGPRs),
// g in LDS, B_lds 16B-granule XOR-swizzled, lgkm-only barriers.
__global__ __launch_bounds__(256, 2)
void conv_mfma(const float* __restrict__ x, const float* __restrict__ coords,
               const float* __restrict__ rot, const float* __restrict__ dist,
               const short* __restrict__ Wa, const float* __restrict__ bias,
               float* __restrict__ out,
               float* __restrict__ sums1, float* __restrict__ sums2) {
  __shared__ float x_win[2][32][XW];          // 48 KB  x window dbuf (f32)
  __shared__ short B_lds[2][BN][BSTRIDE];     // 20 KB  per-tap B dbuf (swizzled granules)
  __shared__ float g_lds[KTAPS][BN];          // 4.6 KB tap weights

  const int tid = threadIdx.x;
  const int b = blockIdx.y;
  const int n0 = blockIdx.x * BN;
  const int wave = tid >> 6;
  const int lane = tid & 63;
  const int col = lane & 15;
  const int quad = lane >> 4;
  const int tl = lane;              // n-pair index for B-build (rows 2tl, 2tl+1)
  const int tkk = wave * 8;         // kk/channel granule base for B-build
  const int xchl = tid >> 3;        // x-stage channel 0..31
  const int xc0 = (tid & 7) * 4;    // x-stage col base

  // ---- tap weights -> g_lds (thread t: point tid&127, taps (tid>>7)+2j)
  {
    const float* cb = coords + (size_t)b * 3 * NPTS;
    const float* rb = rot + (size_t)b * 3 * NPTS;
    const float* db = dist + (size_t)b * NPTS;
    const int nl = tid & 127;
    const int n = n0 + nl;
    float c0x = cb[n], c0y = cb[NPTS + n], c0z = cb[2 * NPTS + n];
    float r0x = rb[n], r0y = rb[NPTS + n], r0z = rb[2 * NPTS + n];
    float d0 = db[n];
    float r0n = r0x * r0x + r0y * r0y + r0z * r0z;
    for (int k = tid >> 7; k < KTAPS; k += 2) {
      int j = n + (k - KTAPS / 2) * DIL;
      float gv = 0.f;
      if (j >= 0 && j < NPTS) {
        float dcx = c0x - cb[j], dcy = c0y - cb[NPTS + j], dcz = c0z - cb[2 * NPTS + j];
        float dc = dcx * dcx + dcy * dcy + dcz * dcz;
        float dd = d0 - db[j];
        dd *= dd;
        float gauss = expf(-(dc + dd) * 0.5f);
        float rjx = rb[j], rjy = rb[NPTS + j], rjz = rb[2 * NPTS + j];
        float num = r0x * rjx + r0y * rjy + r0z * rjz;
        float den = sqrtf(r0n * (rjx * rjx + rjy * rjy + rjz * rjz)) + 1e-8f;
        gv = gauss * fabsf(num / den);
      }
      g_lds[k][nl] = gv;
    }
  }

  const float* xb = x + (size_t)b * CIN * NPTS;
  const int arow0 = (wave * 64 + col) * 32 + quad * 8;  // short offset in a Wa chunk

  // B_lds offsets (shorts), 16B-granule XOR swizzle: phys_g = g ^ ((row>>3)&3)
  const int wr0 = (2 * tl) * BSTRIDE + ((wave ^ ((tl >> 2) & 3)) << 3);
  const int wr1 = wr0 + BSTRIDE;
  int rdoff[8];
#pragma unroll
  for (int j = 0; j < 8; ++j)
    rdoff[j] = (j * 16 + col) * BSTRIDE + ((quad ^ ((2 * j + (col >> 3)) & 3)) << 3);

  float4 xr[3];                     // half-window global->reg stage
  short8 af[2][4];                  // A double buffer

#define LOADAF(AF, CHUNK)                                               \
  {                                                                     \
    const short* p_ = Wa + (size_t)(CHUNK) * 8192 + arow0;              \
    _Pragma("unroll")                                                   \
    for (int m = 0; m < 4; ++m) AF[m] = *(const short8*)(p_ + m * 512); \
  }

#define STAGE_LOAD_H(C8, H)                                             \
  {                                                                     \
    const float* xrow_ = xb + (size_t)((C8) * 32 + xchl) * NPTS;        \
    _Pragma("unroll")                                                   \
    for (int q = 0; q < 3; ++q) {                                       \
      int cw_ = xc0 + ((H) * 3 + q) * 32;                               \
      int jg_ = n0 - XOFF + cw_;                                        \
      float4 v_;                                                        \
      if (jg_ >= 0 && jg_ + 3 < NPTS) {                                 \
        v_ = *(const float4*)&xrow_[jg_];                               \
      } else {                                                          \
        float* e_ = (float*)&v_;                                        \
        _Pragma("unroll")                                               \
        for (int u = 0; u < 4; ++u) {                                   \
          int jj_ = jg_ + u;                                            \
          e_[u] = (jj_ >= 0 && jj_ < NPTS) ? xrow_[jj_] : 0.f;          \
        }                                                               \
      }                                                                 \
      xr[q] = v_;                                                       \
    }                                                                   \
  }

#define STAGE_WRITE_H(XB, H)                                            \
  {                                                                     \
    _Pragma("unroll")                                                   \
    for (int q = 0; q < 3; ++q)                                         \
      *(float4*)&x_win[XB][xchl][xc0 + ((H) * 3 + q) * 32] = xr[q];     \
  }

#define BUILD(K, P, XC)                                                 \
  {                                                                     \
    float2 gk_ = *(const float2*)&g_lds[K][2 * tl];                     \
    const int base_ = 2 * tl + ((K)-KTAPS / 2) * DIL + XOFF;            \
    short8 p0_, p1_;                                                    \
    _Pragma("unroll")                                                   \
    for (int cc = 0; cc < 8; ++cc) {                                    \
      float2 v_ = *(const float2*)&x_win[XC][tkk + cc][base_];          \
      p0_[cc] = (short)f2bf(v_.x * gk_.x);                              \
      p1_[cc] = (short)f2bf(v_.y * gk_.y);                              \
    }                                                                   \
    *(short8*)(&B_lds[P][0][0] + wr0) = p0_;                            \
    *(short8*)(&B_lds[P][0][0] + wr1) = p1_;                            \
  }

#define MFMA_TAP(P, AF)                                                 \
  {                                                                     \
    const short* bb_ = &B_lds[P][0][0];                                 \
    _Pragma("unroll")                                                   \
    for (int j = 0; j < 8; ++j) {                                       \
      short8 bfv_ = *(const short8*)(bb_ + rdoff[j]);                   \
      _Pragma("unroll")                                                 \
      for (int m = 0; m < 4; ++m)                                       \
        acc[m][j] = __builtin_amdgcn_mfma_f32_16x16x32_bf16(AF[m], bfv_, acc[m][j], 0, 0, 0); \
    }                                                                   \
  }

// pure-LDS barrier: no vmcnt drain (global loads stay in flight)
#define BAR()                                                           \
  {                                                                     \
    asm volatile("s_waitcnt lgkmcnt(0)" ::: "memory");                  \
    __builtin_amdgcn_s_barrier();                                       \
    __builtin_amdgcn_sched_barrier(0);                                  \
  }

// tap K (K=0..7): prefetch A for K+1, build B for K+1, MFMA K
#define TAPX(K, C8, AP, XC)                                             \
  {                                                                     \
    LOADAF(af[((K) + 1 + (AP)) & 1], 8 * ((K) + 1) + (C8));             \
    BUILD((K) + 1, ((AP) + (K) + 1) & 1, XC);                           \
    MFMA_TAP(((AP) + (K)) & 1, af[((K) + (AP)) & 1]);                   \
    BAR();                                                              \
  }

#define C8BODY(C8, AP, XC, DN)                                          \
  {                                                                     \
    if (DN) STAGE_LOAD_H((C8) + 1, 0);                                  \
    TAPX(0, C8, AP, XC)                                                 \
    TAPX(1, C8, AP, XC)                                                 \
    TAPX(2, C8, AP, XC)                                                 \
    if (DN) { STAGE_WRITE_H((XC) ^ 1, 0); STAGE_LOAD_H((C8) + 1, 1); }  \
    TAPX(3, C8, AP, XC)                                                 \
    TAPX(4, C8, AP, XC)                                                 \
    TAPX(5, C8, AP, XC)                                                 \
    TAPX(6, C8, AP, XC)                                                 \
    if (DN) STAGE_WRITE_H((XC) ^ 1, 1);                                 \
    TAPX(7, C8, AP, XC)                                                 \
    /* tap 8: prefetch A + build B[0] for next c8 */                    \
    if (DN) {                                                           \
      LOADAF(af[(AP) ^ 1], (C8) + 1);                                   \
      BUILD(0, (AP) ^ 1, (XC) ^ 1);                                     \
    }                                                                   \
    MFMA_TAP((AP), af[(AP)]);                                           \
    BAR();                                                              \
  }

  f32x4 acc[4][8];
#pragma unroll
  for (int m = 0; m < 4; ++m)
#pragma unroll
    for (int j = 0; j < 8; ++j) acc[m][j] = (f32x4)0.f;

  // ---- prologue: stage x_win[0] (both halves), preload A chunk 0, build B[0]
  STAGE_LOAD_H(0, 0);
  STAGE_WRITE_H(0, 0);
  STAGE_LOAD_H(0, 1);
  STAGE_WRITE_H(0, 1);
  LOADAF(af[0], 0);
  __syncthreads();          // x_win[0] + g_lds published
  BUILD(0, 0, 0);           // B[0] of c8=0 -> buf 0
  __syncthreads();          // B[0] published

#pragma unroll 1
  for (int c4 = 0; c4 < 4; ++c4) {
    const int c8a = 2 * c4;
    const int c8b = 2 * c4 + 1;
    const bool dnb = (c4 < 3);
    C8BODY(c8a, 0, 0, true);
    C8BODY(c8b, 1, 1, dnb);
  }

  // ---- epilogue: bias, BN partial sums, store (R0-verified)
  const int obase = wave * 64;
  float* outp = out + (size_t)b * COUT * NPTS + n0;
#pragma unroll
  for (int m = 0; m < 4; ++m) {
    const int o0 = obase + m * 16 + quad * 4;
    const float4 bv = *(const float4*)&bias[o0];
#pragma unroll
    for (int j = 0; j < 8; ++j) {
      acc[m][j][0] += bv.x; acc[m][j][1] += bv.y;
      acc[m][j][2] += bv.z; acc[m][j][3] += bv.w;
    }
#pragma unroll
    for (int r = 0; r < 4; ++r) {
      float s1 = 0.f, s2 = 0.f;
#pragma unroll
      for (int j = 0; j < 8; ++j) {
        float v = acc[m][j][r];
        s1 += v; s2 += v * v;
      }
      s1 += __shfl_xor(s1, 1); s2 += __shfl_xor(s2, 1);
      s1 += __shfl_xor(s1, 2); s2 += __shfl_xor(s2, 2);
      s1 += __shfl_xor(s1, 4); s2 += __shfl_xor(s2, 4);
      s1 += __shfl_xor(s1, 8); s2 += __shfl_xor(s2, 8);
      if (col == 0) {
        atomicAdd(&sums1[o0 + r], s1);
        atomicAdd(&sums2[o0 + r], s2);
      }
#pragma unroll
      for (int j = 0; j < 8; ++j)
        outp[(size_t)(o0 + r) * NPTS + j * 16 + col] = acc[m][j][r];
    }
  }
}

// ---------------------------------------------------------------- BN + ReLU
__global__ __launch_bounds__(256)
void bn_apply(float* __restrict__ out, const float* __restrict__ sums1,
              const float* __restrict__ sums2, const float* __restrict__ gamma,
              const float* __restrict__ beta) {
  int bo = blockIdx.x;
  int o = bo & (COUT - 1);
  const float inv = 1.f / (float)(BB * NPTS);
  float mean = sums1[o] * inv;
  float var = sums2[o] * inv - mean * mean;
  float scale = gamma[o] * rsqrtf(var + BN_EPS);
  float shift = beta[o] - mean * scale;
  float4* p = (float4*)(out + (size_t)bo * NPTS);
  for (int i = threadIdx.x; i < NPTS / 4; i += blockDim.x) {
    float4 v = p[i];
    v.x = fmaxf(fmaf(v.x, scale, shift), 0.f);
    v.y = fmaxf(fmaf(v.y, scale, shift), 0.f);
    v.z = fmaxf(fmaf(v.z, scale, shift), 0.f);
    v.w = fmaxf(fmaf(v.w, scale, shift), 0.f);
    p[i] = v;
  }
}

// ---------------------------------------------------------------- launch
extern "C" void kernel_launch(void* const* d_in, const int* in_sizes, int n_in,
                              void* d_out, int out_size, void* d_ws, size_t ws_size,
                              hipStream_t stream) {
  const float* x      = (const float*)d_in[0];
  const float* coords = (const float*)d_in[1];
  const float* rot    = (const float*)d_in[2];
  const float* dist   = (const float*)d_in[3];
  const float* W      = (const float*)d_in[4];
  const float* bias   = (const float*)d_in[5];
  const float* gamma  = (const float*)d_in[6];
  const float* beta   = (const float*)d_in[7];
  float* out = (float*)d_out;

  float* ws    = (float*)d_ws;
  float* sums1 = ws;                    // 256
  float* sums2 = ws + 256;              // 256
  short* Wa    = (short*)(ws + 512);    // 72*8192 bf16

  pre_kernel<<<2305, 256, 0, stream>>>(W, Wa, sums1);
  conv_mfma<<<dim3(NPTS / BN, BB), 256, 0, stream>>>(x, coords, rot, dist, Wa, bias, out, sums1, sums2);
  bn_apply<<<BB * COUT, 256, 0, stream>>>(out, sums1, sums2, gamma, beta);
}